// Round 7
// baseline (160.267 us; speedup 1.0000x reference)
//
#include <hip/hip_runtime.h>
#include <hip/hip_fp16.h>
#include <math.h>

// Problem constants: N=500, DEG=16, E=8000, B=8, T=12 (BT=96), H=64, F=32
#define N_NODES 500
#define DEG     16
#define E_EDGES 8000
#define BT      96
#define H_      64
#define F_      32
#define ROWS    (BT * N_NODES)   // 48000 rows, r = bt*500 + n
#define SROW    72               // padded LDS row stride in halves (144 B)

typedef _Float16 f16;
typedef f16   half8v  __attribute__((ext_vector_type(8)));
typedef f16   half4v  __attribute__((ext_vector_type(4)));
typedef float f32x4v  __attribute__((ext_vector_type(4)));

__device__ __forceinline__ float sigmoidf_(float x) {
    return 1.0f / (1.0f + __expf(-x));
}

// ---------------------------------------------------------------------------
// Kernel P (fused prep): blocks 0..31 = hyper MLP -> edge_pack {src, h0h1},
// blocks 32..127 = weight transpose -> wTh[c][jj][h] fp16.
// plane c: 0=A_U 1=B_U 2=C_U 3=A_V 4=B_V 5=C_V; A=W3[0].view(128,64),
// B=W3[1], C=b3; U rows 0..63, V rows 64..127.
// ---------------------------------------------------------------------------
__global__ __launch_bounds__(256) void prep_kernel(
        const float* __restrict__ feature, const float* __restrict__ dist,
        const float* __restrict__ W1, const float* __restrict__ b1,
        const float* __restrict__ W2, const float* __restrict__ b2,
        const int* __restrict__ src,
        const float* __restrict__ W3, const float* __restrict__ b3,
        uint2* __restrict__ edge_pack, f16* __restrict__ wTh) {
    if (blockIdx.x >= 32) {
        int i = (blockIdx.x - 32) * 256 + threadIdx.x;
        if (i >= 6 * 64 * 64) return;
        int c  = i >> 12;
        int jj = (i >> 6) & 63;
        int h  = i & 63;
        const float* plane = (c % 3 == 0) ? W3 : (c % 3 == 1) ? (W3 + 8192) : b3;
        int rowbase = (c < 3) ? 0 : 64;
        wTh[i] = (f16)plane[(rowbase + h) * 64 + jj];
        return;
    }

    __shared__ float sW1[65 * 16];
    __shared__ float sb1[16];
    __shared__ float sW2[32];
    __shared__ float sb2[2];
    for (int i = threadIdx.x; i < 65 * 16; i += blockDim.x) sW1[i] = W1[i];
    if (threadIdx.x < 16) sb1[threadIdx.x] = b1[threadIdx.x];
    if (threadIdx.x < 32) sW2[threadIdx.x] = W2[threadIdx.x];
    if (threadIdx.x < 2)  sb2[threadIdx.x] = b2[threadIdx.x];
    __syncthreads();

    int e = blockIdx.x * 256 + threadIdx.x;
    if (e >= E_EDGES) return;
    int s = src[e];
    int d = e >> 4;                 // dst = repeat(arange(500),16)
    float fs[F_], fd[F_];
    const float4* f4 = (const float4*)feature;
    #pragma unroll
    for (int k = 0; k < 8; k++) {
        float4 v = f4[s * 8 + k];
        fs[4*k] = v.x; fs[4*k+1] = v.y; fs[4*k+2] = v.z; fs[4*k+3] = v.w;
    }
    #pragma unroll
    for (int k = 0; k < 8; k++) {
        float4 v = f4[d * 8 + k];
        fd[4*k] = v.x; fd[4*k+1] = v.y; fd[4*k+2] = v.z; fd[4*k+3] = v.w;
    }
    float dv = dist[e];

    float h1v[16];
    #pragma unroll
    for (int m = 0; m < 16; m++) {
        float acc = sb1[m] + dv * sW1[64 * 16 + m];
        #pragma unroll
        for (int f = 0; f < F_; f++) acc += fs[f] * sW1[f * 16 + m];
        #pragma unroll
        for (int f = 0; f < F_; f++) acc += fd[f] * sW1[(F_ + f) * 16 + m];
        h1v[m] = sigmoidf_(acc);
    }
    float o0 = sb2[0], o1 = sb2[1];
    #pragma unroll
    for (int m = 0; m < 16; m++) {
        o0 += h1v[m] * sW2[m * 2 + 0];
        o1 += h1v[m] * sW2[m * 2 + 1];
    }
    __half2 hh = __floats2half2_rn(sigmoidf_(o0), sigmoidf_(o1));
    uint2 ep;
    ep.x = (unsigned)s;
    ep.y = *(unsigned*)&hh;
    edge_pack[e] = ep;
}

// ---------------------------------------------------------------------------
// Kernel B (MFMA): flat GEMM [48000,64] @ [64,384] via mfma_f32_16x16x32_f16.
// 256 thr = 4 waves, 64 rows/block (750 blocks). vs R5: B fragments load
// DIRECTLY from global wTh (49 KB, L2-resident across all blocks) -- no sW
// staging, LDS 64.5 -> 9.2 KB, occupancy 2 -> ~5 blocks/CU, one barrier
// fewer. Outputs half4 {uA,uB,uC,state} / {vA,vB,vC,0}.
// ---------------------------------------------------------------------------
__global__ __launch_bounds__(256) void gemm_pack_mfma(
        const float* __restrict__ state,
        const f16* __restrict__ wTh,
        half4v* __restrict__ UpackH, half4v* __restrict__ VpackH) {
    __shared__ __align__(16) f16 sS[64 * SROW];    // 9.2 KB
    int tid = threadIdx.x;
    int r0  = blockIdx.x * 64;

    // stage S: 64 rows x 64 fp32 -> fp16
    #pragma unroll
    for (int i = 0; i < 4; i++) {
        int f4i = tid + 256 * i;           // 1024 float4
        int row = f4i >> 4, p = f4i & 15;
        float4 v = ((const float4*)state)[(size_t)(r0 + row) * 16 + p];
        half4v hv = { (f16)v.x, (f16)v.y, (f16)v.z, (f16)v.w };
        *(half4v*)&sS[row * SROW + p * 4] = hv;
    }
    __syncthreads();

    int wv   = tid >> 6;
    int lane = tid & 63;
    int col  = lane & 15;
    int quad = lane >> 4;
    int m0   = wv * 16;

    // A fragments: k = kc*32 + quad*8 + j
    half8v a0 = *(const half8v*)&sS[(m0 + col) * SROW + quad * 8];
    half8v a1 = *(const half8v*)&sS[(m0 + col) * SROW + 32 + quad * 8];

    #pragma unroll
    for (int q = 0; q < 4; q++) {
        f32x4v acc[6];
        #pragma unroll
        for (int pl = 0; pl < 6; pl++) {
            int cc0 = pl * 64 + q * 16;
            half8v b0 = *(const half8v*)&wTh[(cc0 + col) * 64 + quad * 8];
            half8v b1 = *(const half8v*)&wTh[(cc0 + col) * 64 + 32 + quad * 8];
            f32x4v a = {0.0f, 0.0f, 0.0f, 0.0f};
            a = __builtin_amdgcn_mfma_f32_16x16x32_f16(a0, b0, a, 0, 0, 0);
            a = __builtin_amdgcn_mfma_f32_16x16x32_f16(a1, b1, a, 0, 0, 0);
            acc[pl] = a;
        }
        f16 sv[4];
        #pragma unroll
        for (int r = 0; r < 4; r++)
            sv[r] = sS[(m0 + quad * 4 + r) * SROW + q * 16 + col];
        #pragma unroll
        for (int r = 0; r < 4; r++) {
            size_t row = (size_t)(r0 + m0 + quad * 4 + r);
            int jj = q * 16 + col;
            half4v up = { (f16)acc[0][r], (f16)acc[1][r], (f16)acc[2][r], sv[r] };
            half4v vp = { (f16)acc[3][r], (f16)acc[4][r], (f16)acc[5][r], (f16)0.0f };
            UpackH[row * H_ + jj] = up;
            VpackH[row * H_ + jj] = vp;
        }
    }
}

// ---------------------------------------------------------------------------
// Kernel C (v4): LDS-staged segment softmax. Grid = 96 bt x 4 jj-quarters
// = 384 blocks. Block stages Upack slice (bt, jj in [jh*16,jh*16+16)) for
// ALL 500 src nodes into 64 KB LDS (Upack read exactly once chip-wide:
// 24.6 MB, vs R6's 393 MB L2/L3 gather), then gathers from LDS.
// Lane map jp = lane&7 (jj pair), slot = lane>>3 (node): an 8-lane group
// reads one contiguous 128 B node-row -> banks 0..31, conflict-free.
// Edge data (src + h0h1, 8 B) in registers per owned node. No XCD/L2
// locality assumptions left.
// ---------------------------------------------------------------------------
__global__ __launch_bounds__(256) void combine_lds(
        const float4* __restrict__ Upack4,   // 2 half4 per float4
        const float4* __restrict__ Vpack4,
        const uint2* __restrict__ edge_pack,
        const float* __restrict__ gate,
        float2* __restrict__ out2) {
    __shared__ float4 sU[N_NODES * 8];   // 64 KB
    int bt = blockIdx.x >> 2;
    int jh = blockIdx.x & 3;
    int tid = threadIdx.x;

    int ubase = bt * N_NODES * 32 + jh * 8;   // float4 index of slice origin
    for (int idx = tid; idx < N_NODES * 8; idx += 256) {
        int n = idx >> 3, ch = idx & 7;
        sU[idx] = Upack4[ubase + n * 32 + ch];
    }
    __syncthreads();

    float sg = sigmoidf_(gate[0]);
    int jp   = tid & 7;
    int slot = tid >> 3;     // 0..31

    const uint4* ep4 = (const uint4*)edge_pack;   // 2 edges per uint4

    for (int n = slot; n < N_NODES; n += 32) {
        // edges of node n: 16 contiguous records = 8 uint4 (L1-broadcast
        // across the 8 lanes sharing this n)
        uint4 E[8];
        #pragma unroll
        for (int k = 0; k < 8; k++) E[k] = ep4[n * 8 + k];

        float4 vraw = Vpack4[ubase + n * 32 + jp];
        float2 vx = __half22float2(*(const __half2*)&vraw.x);  // vA0, vB0
        float2 vy = __half22float2(*(const __half2*)&vraw.y);  // vC0, -
        float2 vz = __half22float2(*(const __half2*)&vraw.z);  // vA1, vB1
        float2 vw = __half22float2(*(const __half2*)&vraw.w);  // vC1, -

        float l0 = 0.0f, num0 = 0.0f, l1 = 0.0f, num1 = 0.0f;
        #pragma unroll
        for (int e = 0; e < DEG; e++) {
            unsigned sx = (e & 1) ? E[e >> 1].z : E[e >> 1].x;
            unsigned hx = (e & 1) ? E[e >> 1].w : E[e >> 1].y;
            float2 hh = __half22float2(*(const __half2*)&hx);
            float4 u = sU[sx * 8 + jp];
            float2 ux = __half22float2(*(const __half2*)&u.x);  // uA0, uB0
            float2 uy = __half22float2(*(const __half2*)&u.y);  // uC0, uS0
            float2 uz = __half22float2(*(const __half2*)&u.z);  // uA1, uB1
            float2 uw = __half22float2(*(const __half2*)&u.w);  // uC1, uS1
            float a0 = hh.x * (ux.x + vx.x) + hh.y * (ux.y + vx.y) + (uy.x + vy.x);
            float a1 = hh.x * (uz.x + vz.x) + hh.y * (uz.y + vz.y) + (uw.x + vw.x);
            a0 = (a0 > 0.0f) ? a0 : 0.01f * a0;    // leaky_relu 0.01
            a1 = (a1 > 0.0f) ? a1 : 0.01f * a1;
            float p0 = __expf(a0);
            float p1 = __expf(a1);
            l0 += p0;  num0 += p0 * uy.y;
            l1 += p1;  num1 += p1 * uw.y;
        }
        float2 r;
        r.x = fmaxf(num0 / l0, 0.0f) * sg;
        r.y = fmaxf(num1 / l1, 0.0f) * sg;
        out2[(size_t)(bt * N_NODES + n) * 32 + jh * 8 + jp] = r;
    }
}

// ---------------------------------------------------------------------------
// Workspace layout (bytes):
//   [0, 64000)                  edge_pack (E uint2)
//   [131072, +49152)            wTh       (6*64*64 fp16)
//   [262144, +24576000)         UpackH    (48000*64 half4)
//   [25165824, +24576000)       VpackH              total ~47.5 MB
// ---------------------------------------------------------------------------
extern "C" void kernel_launch(void* const* d_in, const int* in_sizes, int n_in,
                              void* d_out, int out_size, void* d_ws, size_t ws_size,
                              hipStream_t stream) {
    const float* state   = (const float*)d_in[0];
    const float* feature = (const float*)d_in[1];
    const float* dist    = (const float*)d_in[2];
    const float* W1      = (const float*)d_in[3];
    const float* b1      = (const float*)d_in[4];
    const float* W2      = (const float*)d_in[5];
    const float* b2      = (const float*)d_in[6];
    const float* W3      = (const float*)d_in[7];
    const float* b3      = (const float*)d_in[8];
    const float* gate    = (const float*)d_in[9];
    const int*   src     = (const int*)d_in[10];
    const int*   dst     = (const int*)d_in[11];
    float* out = (float*)d_out;
    (void)dst;

    char* ws = (char*)d_ws;
    uint2*   edge_pack = (uint2*)(ws);
    f16*     wTh       = (f16*)(ws + 131072ULL);
    half4v*  UpackH    = (half4v*)(ws + 262144ULL);
    half4v*  VpackH    = (half4v*)(ws + 25165824ULL);

    hipLaunchKernelGGL(prep_kernel, dim3(128), dim3(256), 0, stream,
                       feature, dist, W1, b1, W2, b2, src, W3, b3,
                       edge_pack, wTh);
    hipLaunchKernelGGL(gemm_pack_mfma, dim3(ROWS / 64), dim3(256), 0, stream,
                       state, wTh, UpackH, VpackH);
    hipLaunchKernelGGL(combine_lds, dim3(BT * 4), dim3(256), 0, stream,
                       (const float4*)UpackH, (const float4*)VpackH,
                       edge_pack, gate, (float2*)out);
}

// Round 8
// 139.767 us; speedup vs baseline: 1.1467x; 1.1467x over previous
//
#include <hip/hip_runtime.h>
#include <hip/hip_fp16.h>
#include <math.h>

// Problem constants: N=500, DEG=16, E=8000, B=8, T=12 (BT=96), H=64, F=32
#define N_NODES 500
#define DEG     16
#define E_EDGES 8000
#define BT      96
#define H_      64
#define F_      32
#define ROWS    (BT * N_NODES)   // 48000 rows, r = bt*500 + n
#define SROW    72               // padded LDS row stride in halves (144 B)

typedef _Float16 f16;
typedef f16   half8v  __attribute__((ext_vector_type(8)));
typedef f16   half4v  __attribute__((ext_vector_type(4)));
typedef float f32x4v  __attribute__((ext_vector_type(4)));

__device__ __forceinline__ float sigmoidf_(float x) {
    return 1.0f / (1.0f + __expf(-x));
}

// ---------------------------------------------------------------------------
// Kernel P (fused prep): blocks 0..31 = hyper MLP -> edge_pack {src, h0h1},
// blocks 32..127 = weight transpose -> wTh[c][jj][h] fp16.
// plane c: 0=A_U 1=B_U 2=C_U 3=A_V 4=B_V 5=C_V; A=W3[0].view(128,64),
// B=W3[1], C=b3; U rows 0..63, V rows 64..127.
// ---------------------------------------------------------------------------
__global__ __launch_bounds__(256) void prep_kernel(
        const float* __restrict__ feature, const float* __restrict__ dist,
        const float* __restrict__ W1, const float* __restrict__ b1,
        const float* __restrict__ W2, const float* __restrict__ b2,
        const int* __restrict__ src,
        const float* __restrict__ W3, const float* __restrict__ b3,
        uint2* __restrict__ edge_pack, f16* __restrict__ wTh) {
    if (blockIdx.x >= 32) {
        int i = (blockIdx.x - 32) * 256 + threadIdx.x;
        if (i >= 6 * 64 * 64) return;
        int c  = i >> 12;
        int jj = (i >> 6) & 63;
        int h  = i & 63;
        const float* plane = (c % 3 == 0) ? W3 : (c % 3 == 1) ? (W3 + 8192) : b3;
        int rowbase = (c < 3) ? 0 : 64;
        wTh[i] = (f16)plane[(rowbase + h) * 64 + jj];
        return;
    }

    __shared__ float sW1[65 * 16];
    __shared__ float sb1[16];
    __shared__ float sW2[32];
    __shared__ float sb2[2];
    for (int i = threadIdx.x; i < 65 * 16; i += blockDim.x) sW1[i] = W1[i];
    if (threadIdx.x < 16) sb1[threadIdx.x] = b1[threadIdx.x];
    if (threadIdx.x < 32) sW2[threadIdx.x] = W2[threadIdx.x];
    if (threadIdx.x < 2)  sb2[threadIdx.x] = b2[threadIdx.x];
    __syncthreads();

    int e = blockIdx.x * 256 + threadIdx.x;
    if (e >= E_EDGES) return;
    int s = src[e];
    int d = e >> 4;                 // dst = repeat(arange(500),16)
    float fs[F_], fd[F_];
    const float4* f4 = (const float4*)feature;
    #pragma unroll
    for (int k = 0; k < 8; k++) {
        float4 v = f4[s * 8 + k];
        fs[4*k] = v.x; fs[4*k+1] = v.y; fs[4*k+2] = v.z; fs[4*k+3] = v.w;
    }
    #pragma unroll
    for (int k = 0; k < 8; k++) {
        float4 v = f4[d * 8 + k];
        fd[4*k] = v.x; fd[4*k+1] = v.y; fd[4*k+2] = v.z; fd[4*k+3] = v.w;
    }
    float dv = dist[e];

    float h1v[16];
    #pragma unroll
    for (int m = 0; m < 16; m++) {
        float acc = sb1[m] + dv * sW1[64 * 16 + m];
        #pragma unroll
        for (int f = 0; f < F_; f++) acc += fs[f] * sW1[f * 16 + m];
        #pragma unroll
        for (int f = 0; f < F_; f++) acc += fd[f] * sW1[(F_ + f) * 16 + m];
        h1v[m] = sigmoidf_(acc);
    }
    float o0 = sb2[0], o1 = sb2[1];
    #pragma unroll
    for (int m = 0; m < 16; m++) {
        o0 += h1v[m] * sW2[m * 2 + 0];
        o1 += h1v[m] * sW2[m * 2 + 1];
    }
    __half2 hh = __floats2half2_rn(sigmoidf_(o0), sigmoidf_(o1));
    uint2 ep;
    ep.x = (unsigned)s;
    ep.y = *(unsigned*)&hh;
    edge_pack[e] = ep;
}

// ---------------------------------------------------------------------------
// Kernel B (MFMA): flat GEMM [48000,64] @ [64,384] via mfma_f32_16x16x32_f16.
// REVERTED to the R5 version (sW staged in LDS): R7's global-B variant
// coincided with a regression; this config is from the 133 us round.
// ---------------------------------------------------------------------------
__global__ __launch_bounds__(256) void gemm_pack_mfma(
        const float* __restrict__ state,
        const f16* __restrict__ wTh,
        half4v* __restrict__ UpackH, half4v* __restrict__ VpackH) {
    __shared__ __align__(16) f16 sW[384 * SROW];   // 55.3 KB
    __shared__ __align__(16) f16 sS[64 * SROW];    //  9.2 KB
    int tid = threadIdx.x;
    int r0  = blockIdx.x * 64;

    #pragma unroll
    for (int i = 0; i < 12; i++) {
        int idx = tid + 256 * i;           // 3072 16B chunks of W
        int cc = idx >> 3, p = idx & 7;
        *(float4*)&sW[cc * SROW + p * 8] = ((const float4*)wTh)[idx];
    }
    #pragma unroll
    for (int i = 0; i < 4; i++) {
        int f4i = tid + 256 * i;           // 1024 float4 of S
        int row = f4i >> 4, p = f4i & 15;
        float4 v = ((const float4*)state)[(size_t)(r0 + row) * 16 + p];
        half4v hv = { (f16)v.x, (f16)v.y, (f16)v.z, (f16)v.w };
        *(half4v*)&sS[row * SROW + p * 4] = hv;
    }
    __syncthreads();

    int wv   = tid >> 6;
    int lane = tid & 63;
    int col  = lane & 15;
    int quad = lane >> 4;
    int m0   = wv * 16;

    half8v a0 = *(const half8v*)&sS[(m0 + col) * SROW + quad * 8];
    half8v a1 = *(const half8v*)&sS[(m0 + col) * SROW + 32 + quad * 8];

    #pragma unroll
    for (int q = 0; q < 4; q++) {
        f32x4v acc[6];
        #pragma unroll
        for (int pl = 0; pl < 6; pl++) {
            int cc0 = pl * 64 + q * 16;
            half8v b0 = *(const half8v*)&sW[(cc0 + col) * SROW + quad * 8];
            half8v b1 = *(const half8v*)&sW[(cc0 + col) * SROW + 32 + quad * 8];
            f32x4v a = {0.0f, 0.0f, 0.0f, 0.0f};
            a = __builtin_amdgcn_mfma_f32_16x16x32_f16(a0, b0, a, 0, 0, 0);
            a = __builtin_amdgcn_mfma_f32_16x16x32_f16(a1, b1, a, 0, 0, 0);
            acc[pl] = a;
        }
        f16 sv[4];
        #pragma unroll
        for (int r = 0; r < 4; r++)
            sv[r] = sS[(m0 + quad * 4 + r) * SROW + q * 16 + col];
        #pragma unroll
        for (int r = 0; r < 4; r++) {
            size_t row = (size_t)(r0 + m0 + quad * 4 + r);
            int jj = q * 16 + col;
            half4v up = { (f16)acc[0][r], (f16)acc[1][r], (f16)acc[2][r], sv[r] };
            half4v vp = { (f16)acc[3][r], (f16)acc[4][r], (f16)acc[5][r], (f16)0.0f };
            UpackH[row * H_ + jj] = up;
            VpackH[row * H_ + jj] = vp;
        }
    }
}

// ---------------------------------------------------------------------------
// Kernel C (v5): LDS-staged segment softmax, occupancy+conflict fixed.
// Grid = 96 bt x 4 jj-quarters = 384 blocks of 512 thr (8 waves).
// LDS 64 KB slice -> 2 blocks/CU x 8 waves = 16 waves/CU (R7: 256 thr ->
// 8 waves/CU, Occupancy 11%, VALU couldn't be hidden).
// Bank fix: node-row chunk c stored at physical slot c^(n&7) -> rows no
// longer all start at bank 0 (R7: 1.1M conflict cycles from alignment).
// Lane map: jp = tid&7 (jj pair), slot = tid>>3 (64 slots, 8 n-iters).
// ---------------------------------------------------------------------------
__global__ __launch_bounds__(512, 4) void combine_lds(
        const float4* __restrict__ Upack4,   // 2 half4 per float4
        const float4* __restrict__ Vpack4,
        const uint2* __restrict__ edge_pack,
        const float* __restrict__ gate,
        float2* __restrict__ out2) {
    __shared__ float4 sU[N_NODES * 8];   // 64 KB
    int bt = blockIdx.x >> 2;
    int jh = blockIdx.x & 3;
    int tid = threadIdx.x;

    int ubase = bt * N_NODES * 32 + jh * 8;   // float4 index of slice origin
    for (int idx = tid; idx < N_NODES * 8; idx += 512) {
        int n = idx >> 3, c = idx & 7;
        sU[n * 8 + (c ^ (n & 7))] = Upack4[ubase + n * 32 + c];
    }
    __syncthreads();

    float sg = sigmoidf_(gate[0]);
    int jp   = tid & 7;
    int slot = tid >> 3;     // 0..63

    const uint4* ep4 = (const uint4*)edge_pack;   // 2 edges per uint4

    for (int n = slot; n < N_NODES; n += 64) {
        uint4 E[8];
        #pragma unroll
        for (int k = 0; k < 8; k++) E[k] = ep4[n * 8 + k];

        float4 vraw = Vpack4[ubase + n * 32 + jp];
        float2 vx = __half22float2(*(const __half2*)&vraw.x);  // vA0, vB0
        float2 vy = __half22float2(*(const __half2*)&vraw.y);  // vC0, -
        float2 vz = __half22float2(*(const __half2*)&vraw.z);  // vA1, vB1
        float2 vw = __half22float2(*(const __half2*)&vraw.w);  // vC1, -

        float l0 = 0.0f, num0 = 0.0f, l1 = 0.0f, num1 = 0.0f;
        #pragma unroll
        for (int e = 0; e < DEG; e++) {
            unsigned sx = (e & 1) ? E[e >> 1].z : E[e >> 1].x;
            unsigned hx = (e & 1) ? E[e >> 1].w : E[e >> 1].y;
            float2 hh = __half22float2(*(const __half2*)&hx);
            float4 u = sU[sx * 8 + (jp ^ (sx & 7))];
            float2 ux = __half22float2(*(const __half2*)&u.x);  // uA0, uB0
            float2 uy = __half22float2(*(const __half2*)&u.y);  // uC0, uS0
            float2 uz = __half22float2(*(const __half2*)&u.z);  // uA1, uB1
            float2 uw = __half22float2(*(const __half2*)&u.w);  // uC1, uS1
            float a0 = fmaf(hh.x, ux.x + vx.x, fmaf(hh.y, ux.y + vx.y, uy.x + vy.x));
            float a1 = fmaf(hh.x, uz.x + vz.x, fmaf(hh.y, uz.y + vz.y, uw.x + vw.x));
            a0 = fmaxf(a0, 0.01f * a0);            // leaky_relu 0.01
            a1 = fmaxf(a1, 0.01f * a1);
            float p0 = __expf(a0);
            float p1 = __expf(a1);
            l0 += p0;  num0 = fmaf(p0, uy.y, num0);
            l1 += p1;  num1 = fmaf(p1, uw.y, num1);
        }
        float2 r;
        r.x = fmaxf(num0 / l0, 0.0f) * sg;
        r.y = fmaxf(num1 / l1, 0.0f) * sg;
        out2[(size_t)(bt * N_NODES + n) * 32 + jh * 8 + jp] = r;
    }
}

// ---------------------------------------------------------------------------
// Workspace layout (bytes):
//   [0, 64000)                  edge_pack (E uint2)
//   [131072, +49152)            wTh       (6*64*64 fp16)
//   [262144, +24576000)         UpackH    (48000*64 half4)
//   [25165824, +24576000)       VpackH              total ~47.5 MB
// ---------------------------------------------------------------------------
extern "C" void kernel_launch(void* const* d_in, const int* in_sizes, int n_in,
                              void* d_out, int out_size, void* d_ws, size_t ws_size,
                              hipStream_t stream) {
    const float* state   = (const float*)d_in[0];
    const float* feature = (const float*)d_in[1];
    const float* dist    = (const float*)d_in[2];
    const float* W1      = (const float*)d_in[3];
    const float* b1      = (const float*)d_in[4];
    const float* W2      = (const float*)d_in[5];
    const float* b2      = (const float*)d_in[6];
    const float* W3      = (const float*)d_in[7];
    const float* b3      = (const float*)d_in[8];
    const float* gate    = (const float*)d_in[9];
    const int*   src     = (const int*)d_in[10];
    const int*   dst     = (const int*)d_in[11];
    float* out = (float*)d_out;
    (void)dst;

    char* ws = (char*)d_ws;
    uint2*   edge_pack = (uint2*)(ws);
    f16*     wTh       = (f16*)(ws + 131072ULL);
    half4v*  UpackH    = (half4v*)(ws + 262144ULL);
    half4v*  VpackH    = (half4v*)(ws + 25165824ULL);

    hipLaunchKernelGGL(prep_kernel, dim3(128), dim3(256), 0, stream,
                       feature, dist, W1, b1, W2, b2, src, W3, b3,
                       edge_pack, wTh);
    hipLaunchKernelGGL(gemm_pack_mfma, dim3(ROWS / 64), dim3(256), 0, stream,
                       state, wTh, UpackH, VpackH);
    hipLaunchKernelGGL(combine_lds, dim3(BT * 4), dim3(512), 0, stream,
                       (const float4*)UpackH, (const float4*)VpackH,
                       edge_pack, gate, (float2*)out);
}

// Round 9
// 134.941 us; speedup vs baseline: 1.1877x; 1.0358x over previous
//
#include <hip/hip_runtime.h>
#include <hip/hip_fp16.h>
#include <math.h>

// Problem constants: N=500, DEG=16, E=8000, B=8, T=12 (BT=96), H=64, F=32
#define N_NODES 500
#define DEG     16
#define E_EDGES 8000
#define BT      96
#define H_      64
#define F_      32

typedef _Float16 f16;
typedef f16   half8v  __attribute__((ext_vector_type(8)));
typedef float f32x4v  __attribute__((ext_vector_type(4)));

__device__ __forceinline__ float sigmoidf_(float x) {
    return 1.0f / (1.0f + __expf(-x));
}

// ---------------------------------------------------------------------------
// Kernel P (fused prep): blocks 0..31 = hyper MLP -> edge_pack {src, h0h1},
// blocks 32..127 = weight transpose -> wTh[c][jj][h] fp16 ([col][k] layout).
// plane c: 0=A_U 1=B_U 2=C_U 3=A_V 4=B_V 5=C_V; A=W3[0].view(128,64),
// B=W3[1], C=b3; U rows 0..63, V rows 64..127.
// ---------------------------------------------------------------------------
__global__ __launch_bounds__(256) void prep_kernel(
        const float* __restrict__ feature, const float* __restrict__ dist,
        const float* __restrict__ W1, const float* __restrict__ b1,
        const float* __restrict__ W2, const float* __restrict__ b2,
        const int* __restrict__ src,
        const float* __restrict__ W3, const float* __restrict__ b3,
        uint2* __restrict__ edge_pack, f16* __restrict__ wTh) {
    if (blockIdx.x >= 32) {
        int i = (blockIdx.x - 32) * 256 + threadIdx.x;
        if (i >= 6 * 64 * 64) return;
        int c  = i >> 12;
        int jj = (i >> 6) & 63;
        int h  = i & 63;
        const float* plane = (c % 3 == 0) ? W3 : (c % 3 == 1) ? (W3 + 8192) : b3;
        int rowbase = (c < 3) ? 0 : 64;
        wTh[i] = (f16)plane[(rowbase + h) * 64 + jj];
        return;
    }

    __shared__ float sW1[65 * 16];
    __shared__ float sb1[16];
    __shared__ float sW2[32];
    __shared__ float sb2[2];
    for (int i = threadIdx.x; i < 65 * 16; i += blockDim.x) sW1[i] = W1[i];
    if (threadIdx.x < 16) sb1[threadIdx.x] = b1[threadIdx.x];
    if (threadIdx.x < 32) sW2[threadIdx.x] = W2[threadIdx.x];
    if (threadIdx.x < 2)  sb2[threadIdx.x] = b2[threadIdx.x];
    __syncthreads();

    int e = blockIdx.x * 256 + threadIdx.x;
    if (e >= E_EDGES) return;
    int s = src[e];
    int d = e >> 4;                 // dst = repeat(arange(500),16)
    float fs[F_], fd[F_];
    const float4* f4 = (const float4*)feature;
    #pragma unroll
    for (int k = 0; k < 8; k++) {
        float4 v = f4[s * 8 + k];
        fs[4*k] = v.x; fs[4*k+1] = v.y; fs[4*k+2] = v.z; fs[4*k+3] = v.w;
    }
    #pragma unroll
    for (int k = 0; k < 8; k++) {
        float4 v = f4[d * 8 + k];
        fd[4*k] = v.x; fd[4*k+1] = v.y; fd[4*k+2] = v.z; fd[4*k+3] = v.w;
    }
    float dv = dist[e];

    float h1v[16];
    #pragma unroll
    for (int m = 0; m < 16; m++) {
        float acc = sb1[m] + dv * sW1[64 * 16 + m];
        #pragma unroll
        for (int f = 0; f < F_; f++) acc += fs[f] * sW1[f * 16 + m];
        #pragma unroll
        for (int f = 0; f < F_; f++) acc += fd[f] * sW1[(F_ + f) * 16 + m];
        h1v[m] = sigmoidf_(acc);
    }
    float o0 = sb2[0], o1 = sb2[1];
    #pragma unroll
    for (int m = 0; m < 16; m++) {
        o0 += h1v[m] * sW2[m * 2 + 0];
        o1 += h1v[m] * sW2[m * 2 + 1];
    }
    __half2 hh = __floats2half2_rn(sigmoidf_(o0), sigmoidf_(o1));
    uint2 ep;
    ep.x = (unsigned)s;
    ep.y = *(unsigned*)&hh;
    edge_pack[e] = ep;
}

// ---------------------------------------------------------------------------
// Kernel F (fused GEMM + segment softmax). Grid = 96 bt x 8 jj-eighths
// = 768 blocks x 512 thr (8 waves). No Upack/Vpack in HBM at all.
//
// Phase 1: slice GEMM [500,64] @ [64, 8jj x 6planes] via mfma_f32_16x16x32:
//   3 col-tiles of 16 = 2 planes x 8 jj each; B-frags in regs (from wTh,
//   L2-hot); A-frags fp32->fp16 straight from global state; 4 passes of
//   8 waves x 16 rows. Epilogue scatters per-(n,jj) plane values into LDS:
//     sU[n][jp] = {uA0,uB0,uC0,state0, uA1,uB1,uC1,state1}  (float4)
//     sV[n][jp] = {vA0,vB0,vC0,  -   , vA1,vB1,vC1,  -   }
//   row stride 5 float4 (80 B) -> row start banks cycle 8 ways, breaking
//   the all-rows-start-at-bank-0 pattern that cost R7 1.1M conflict cycles.
// Phase 2: R8's combine loop, U and V both from LDS, write only the output.
// LDS 80 KB -> 2 blocks/CU = 16 waves/CU; 768 blocks = exactly 3 rounds.
// ---------------------------------------------------------------------------
__global__ __launch_bounds__(512, 4) void fused_kernel(
        const float* __restrict__ state,
        const f16* __restrict__ wTh,
        const uint2* __restrict__ edge_pack,
        const float* __restrict__ gate,
        float2* __restrict__ out2) {
    __shared__ float4 sU[N_NODES * 5];   // 40 KB
    __shared__ float4 sV[N_NODES * 5];   // 40 KB

    int bt  = blockIdx.x >> 3;
    int jh  = blockIdx.x & 7;
    int tid = threadIdx.x;
    int wv   = tid >> 6;
    int lane = tid & 63;
    int col  = lane & 15;
    int quad = lane >> 4;

    // B fragments: tile t covers planes {2t (col<8), 2t+1 (col>=8)} x 8 jj
    int jjglob = jh * 8 + (col & 7);
    half8v bfr[3][2];
    #pragma unroll
    for (int t = 0; t < 3; t++) {
        int plane = 2 * t + (col >> 3);
        const f16* wp = wTh + (plane * 64 + jjglob) * 64;
        bfr[t][0] = *(const half8v*)&wp[quad * 8];
        bfr[t][1] = *(const half8v*)&wp[32 + quad * 8];
    }

    const size_t sbase = (size_t)bt * N_NODES * H_;
    f16* sUh = (f16*)sU;
    f16* sVh = (f16*)sV;

    // ---- Phase 1: GEMM into LDS pack
    #pragma unroll 1
    for (int pass = 0; pass < 4; pass++) {
        int row0 = pass * 128 + wv * 16;
        int arow = row0 + col;
        int arowc = arow < N_NODES ? arow : N_NODES - 1;   // clamp tail reads
        const float* srow = state + sbase + (size_t)arowc * H_;
        float4 p0 = *(const float4*)&srow[quad * 8];
        float4 p1 = *(const float4*)&srow[quad * 8 + 4];
        float4 p2 = *(const float4*)&srow[32 + quad * 8];
        float4 p3 = *(const float4*)&srow[32 + quad * 8 + 4];
        half8v a0 = { (f16)p0.x,(f16)p0.y,(f16)p0.z,(f16)p0.w,
                      (f16)p1.x,(f16)p1.y,(f16)p1.z,(f16)p1.w };
        half8v a1 = { (f16)p2.x,(f16)p2.y,(f16)p2.z,(f16)p2.w,
                      (f16)p3.x,(f16)p3.y,(f16)p3.z,(f16)p3.w };

        f32x4v acc[3];
        #pragma unroll
        for (int t = 0; t < 3; t++) {
            f32x4v a = {0.0f, 0.0f, 0.0f, 0.0f};
            a = __builtin_amdgcn_mfma_f32_16x16x32_f16(a0, bfr[t][0], a, 0, 0, 0);
            a = __builtin_amdgcn_mfma_f32_16x16x32_f16(a1, bfr[t][1], a, 0, 0, 0);
            acc[t] = a;
        }

        // epilogue: C row = row0 + quad*4 + r; col c -> (plane, jjloc)
        int jp  = (col & 7) >> 1;
        int sub = col & 1;
        #pragma unroll
        for (int r = 0; r < 4; r++) {
            int row = row0 + quad * 4 + r;
            if (row < N_NODES) {
                int hb = (row * 5 + jp) * 8 + sub * 4;
                #pragma unroll
                for (int t = 0; t < 3; t++) {
                    int plane = 2 * t + (col >> 3);
                    f16 v = (f16)acc[t][r];
                    if (plane < 3) sUh[hb + plane] = v;
                    else           sVh[hb + (plane - 3)] = v;
                }
                if (col < 8) {   // one writer per (row, jj): state value
                    float svv = state[sbase + (size_t)row * H_ + jjglob];
                    sUh[hb + 3] = (f16)svv;
                }
            }
        }
    }
    __syncthreads();

    // ---- Phase 2: segment softmax from LDS
    float sg = sigmoidf_(gate[0]);
    int jp   = tid & 3;      // jj pair within the eighth
    int slot = tid >> 2;     // 0..127

    const uint4* ep4 = (const uint4*)edge_pack;   // 2 edges per uint4

    #pragma unroll 1
    for (int n = slot; n < N_NODES; n += 128) {
        uint4 E[8];
        #pragma unroll
        for (int k = 0; k < 8; k++) E[k] = ep4[n * 8 + k];

        float4 vraw = sV[n * 5 + jp];
        float2 vx = __half22float2(*(const __half2*)&vraw.x);  // vA0, vB0
        float2 vy = __half22float2(*(const __half2*)&vraw.y);  // vC0, -
        float2 vz = __half22float2(*(const __half2*)&vraw.z);  // vA1, vB1
        float2 vw = __half22float2(*(const __half2*)&vraw.w);  // vC1, -

        float l0 = 0.0f, num0 = 0.0f, l1 = 0.0f, num1 = 0.0f;
        #pragma unroll
        for (int e = 0; e < DEG; e++) {
            unsigned sx = (e & 1) ? E[e >> 1].z : E[e >> 1].x;
            unsigned hx = (e & 1) ? E[e >> 1].w : E[e >> 1].y;
            float2 hh = __half22float2(*(const __half2*)&hx);
            float4 u = sU[sx * 5 + jp];
            float2 ux = __half22float2(*(const __half2*)&u.x);  // uA0, uB0
            float2 uy = __half22float2(*(const __half2*)&u.y);  // uC0, uS0
            float2 uz = __half22float2(*(const __half2*)&u.z);  // uA1, uB1
            float2 uw = __half22float2(*(const __half2*)&u.w);  // uC1, uS1
            float a0 = fmaf(hh.x, ux.x + vx.x, fmaf(hh.y, ux.y + vx.y, uy.x + vy.x));
            float a1 = fmaf(hh.x, uz.x + vz.x, fmaf(hh.y, uz.y + vz.y, uw.x + vw.x));
            a0 = fmaxf(a0, 0.01f * a0);            // leaky_relu 0.01
            a1 = fmaxf(a1, 0.01f * a1);
            float p0 = __expf(a0);
            float p1 = __expf(a1);
            l0 += p0;  num0 = fmaf(p0, uy.y, num0);
            l1 += p1;  num1 = fmaf(p1, uw.y, num1);
        }
        float2 r;
        r.x = fmaxf(num0 / l0, 0.0f) * sg;
        r.y = fmaxf(num1 / l1, 0.0f) * sg;
        out2[((size_t)bt * N_NODES + n) * 32 + jh * 4 + jp] = r;
    }
}

// ---------------------------------------------------------------------------
// Workspace layout (bytes):
//   [0, 64000)        edge_pack (E uint2)
//   [131072, +49152)  wTh       (6*64*64 fp16)       total < 0.2 MB
// ---------------------------------------------------------------------------
extern "C" void kernel_launch(void* const* d_in, const int* in_sizes, int n_in,
                              void* d_out, int out_size, void* d_ws, size_t ws_size,
                              hipStream_t stream) {
    const float* state   = (const float*)d_in[0];
    const float* feature = (const float*)d_in[1];
    const float* dist    = (const float*)d_in[2];
    const float* W1      = (const float*)d_in[3];
    const float* b1      = (const float*)d_in[4];
    const float* W2      = (const float*)d_in[5];
    const float* b2      = (const float*)d_in[6];
    const float* W3      = (const float*)d_in[7];
    const float* b3      = (const float*)d_in[8];
    const float* gate    = (const float*)d_in[9];
    const int*   src     = (const int*)d_in[10];
    const int*   dst     = (const int*)d_in[11];
    float* out = (float*)d_out;
    (void)dst;

    char* ws = (char*)d_ws;
    uint2* edge_pack = (uint2*)(ws);
    f16*   wTh       = (f16*)(ws + 131072ULL);

    hipLaunchKernelGGL(prep_kernel, dim3(128), dim3(256), 0, stream,
                       feature, dist, W1, b1, W2, b2, src, W3, b3,
                       edge_pack, wTh);
    hipLaunchKernelGGL(fused_kernel, dim3(BT * 8), dim3(512), 0, stream,
                       state, wTh, edge_pack, gate, (float2*)out);
}

// Round 10
// 130.194 us; speedup vs baseline: 1.2310x; 1.0365x over previous
//
#include <hip/hip_runtime.h>
#include <hip/hip_fp16.h>
#include <math.h>

// Problem constants: N=500, DEG=16, E=8000, B=8, T=12 (BT=96), H=64, F=32
#define N_NODES 500
#define DEG     16
#define E_EDGES 8000
#define BT      96
#define H_      64
#define F_      32

typedef _Float16 f16;
typedef f16   half8v  __attribute__((ext_vector_type(8)));
typedef float f32x4v  __attribute__((ext_vector_type(4)));

#if __has_builtin(__builtin_amdgcn_exp2f)
#define EXP2F(x) __builtin_amdgcn_exp2f(x)
#else
#define EXP2F(x) exp2f(x)
#endif

#define LOG2E 1.44269504088896f

__device__ __forceinline__ float sigmoidf_(float x) {
    return 1.0f / (1.0f + __expf(-x));
}

// ---------------------------------------------------------------------------
// Kernel P (fused prep): blocks 0..31 = hyper MLP -> edge_pack
// {src*80 (LDS byte offset), h0h1 fp16x2}; blocks 32..127 = weight transpose
// -> wTh[c][jj][h] fp16, PRE-SCALED by log2(e) so the fused kernel can use
// exp2 directly (leaky_relu commutes with a positive scale).
// plane c: 0=A_U 1=B_U 2=C_U 3=A_V 4=B_V 5=C_V; A=W3[0].view(128,64),
// B=W3[1], C=b3; U rows 0..63, V rows 64..127.
// ---------------------------------------------------------------------------
__global__ __launch_bounds__(256) void prep_kernel(
        const float* __restrict__ feature, const float* __restrict__ dist,
        const float* __restrict__ W1, const float* __restrict__ b1,
        const float* __restrict__ W2, const float* __restrict__ b2,
        const int* __restrict__ src,
        const float* __restrict__ W3, const float* __restrict__ b3,
        uint2* __restrict__ edge_pack, f16* __restrict__ wTh) {
    if (blockIdx.x >= 32) {
        int i = (blockIdx.x - 32) * 256 + threadIdx.x;
        if (i >= 6 * 64 * 64) return;
        int c  = i >> 12;
        int jj = (i >> 6) & 63;
        int h  = i & 63;
        const float* plane = (c % 3 == 0) ? W3 : (c % 3 == 1) ? (W3 + 8192) : b3;
        int rowbase = (c < 3) ? 0 : 64;
        wTh[i] = (f16)(plane[(rowbase + h) * 64 + jj] * LOG2E);
        return;
    }

    __shared__ float sW1[65 * 16];
    __shared__ float sb1[16];
    __shared__ float sW2[32];
    __shared__ float sb2[2];
    for (int i = threadIdx.x; i < 65 * 16; i += blockDim.x) sW1[i] = W1[i];
    if (threadIdx.x < 16) sb1[threadIdx.x] = b1[threadIdx.x];
    if (threadIdx.x < 32) sW2[threadIdx.x] = W2[threadIdx.x];
    if (threadIdx.x < 2)  sb2[threadIdx.x] = b2[threadIdx.x];
    __syncthreads();

    int e = blockIdx.x * 256 + threadIdx.x;
    if (e >= E_EDGES) return;
    int s = src[e];
    int d = e >> 4;                 // dst = repeat(arange(500),16)
    float fs[F_], fd[F_];
    const float4* f4 = (const float4*)feature;
    #pragma unroll
    for (int k = 0; k < 8; k++) {
        float4 v = f4[s * 8 + k];
        fs[4*k] = v.x; fs[4*k+1] = v.y; fs[4*k+2] = v.z; fs[4*k+3] = v.w;
    }
    #pragma unroll
    for (int k = 0; k < 8; k++) {
        float4 v = f4[d * 8 + k];
        fd[4*k] = v.x; fd[4*k+1] = v.y; fd[4*k+2] = v.z; fd[4*k+3] = v.w;
    }
    float dv = dist[e];

    float h1v[16];
    #pragma unroll
    for (int m = 0; m < 16; m++) {
        float acc = sb1[m] + dv * sW1[64 * 16 + m];
        #pragma unroll
        for (int f = 0; f < F_; f++) acc += fs[f] * sW1[f * 16 + m];
        #pragma unroll
        for (int f = 0; f < F_; f++) acc += fd[f] * sW1[(F_ + f) * 16 + m];
        h1v[m] = sigmoidf_(acc);
    }
    float o0 = sb2[0], o1 = sb2[1];
    #pragma unroll
    for (int m = 0; m < 16; m++) {
        o0 += h1v[m] * sW2[m * 2 + 0];
        o1 += h1v[m] * sW2[m * 2 + 1];
    }
    __half2 hh = __floats2half2_rn(sigmoidf_(o0), sigmoidf_(o1));
    uint2 ep;
    ep.x = (unsigned)(s * 80);      // pre-multiplied sU row byte-offset
    ep.y = *(unsigned*)&hh;
    edge_pack[e] = ep;
}

// ---------------------------------------------------------------------------
// Kernel F (fused GEMM + segment softmax). Grid = 8 jh x 96 bt, jh-MAJOR:
// blockIdx = jh*96 + bt, so the 8 blocks sharing a bt are 96 apart ->
// same XCD under %8 round-robin -> the 128 KB state slice stays in that
// XCD's L2 (R9 bt-major spread them over all XCDs: FETCH 48.5 MB = 4x
// compulsory). 512 thr (8 waves), LDS 80 KB -> 2 blocks/CU.
//
// Phase 1: slice GEMM [500,64] @ [64, 8jj x 6planes] via mfma_f32_16x16x32.
//   Pass loop left to the compiler to pipeline (R9 pinned it serial).
// Phase 2: segment softmax from LDS, with the 8xuint4 edge records
//   DOUBLE-BUFFERED (prefetch n+128 during n) to break the global-load ->
//   LDS-gather serial chain that left R9 latency-bound at 31% occupancy.
// ---------------------------------------------------------------------------
__global__ __launch_bounds__(512, 4) void fused_kernel(
        const float* __restrict__ state,
        const f16* __restrict__ wTh,
        const uint2* __restrict__ edge_pack,
        const float* __restrict__ gate,
        float2* __restrict__ out2) {
    __shared__ float4 sU[N_NODES * 5];   // 40 KB, 80 B per node row
    __shared__ float4 sV[N_NODES * 5];   // 40 KB

    int bt  = blockIdx.x % BT;
    int jh  = blockIdx.x / BT;
    int tid = threadIdx.x;
    int wv   = tid >> 6;
    int lane = tid & 63;
    int col  = lane & 15;
    int quad = lane >> 4;

    // B fragments: tile t covers planes {2t (col<8), 2t+1 (col>=8)} x 8 jj
    int jjglob = jh * 8 + (col & 7);
    half8v bfr[3][2];
    #pragma unroll
    for (int t = 0; t < 3; t++) {
        int plane = 2 * t + (col >> 3);
        const f16* wp = wTh + (plane * 64 + jjglob) * 64;
        bfr[t][0] = *(const half8v*)&wp[quad * 8];
        bfr[t][1] = *(const half8v*)&wp[32 + quad * 8];
    }

    const size_t sbase = (size_t)bt * N_NODES * H_;
    f16* sUh = (f16*)sU;
    f16* sVh = (f16*)sV;

    // ---- Phase 1: GEMM into LDS pack
    for (int pass = 0; pass < 4; pass++) {
        int row0 = pass * 128 + wv * 16;
        int arow = row0 + col;
        int arowc = arow < N_NODES ? arow : N_NODES - 1;   // clamp tail reads
        const float* srow = state + sbase + (size_t)arowc * H_;
        float4 p0 = *(const float4*)&srow[quad * 8];
        float4 p1 = *(const float4*)&srow[quad * 8 + 4];
        float4 p2 = *(const float4*)&srow[32 + quad * 8];
        float4 p3 = *(const float4*)&srow[32 + quad * 8 + 4];
        half8v a0 = { (f16)p0.x,(f16)p0.y,(f16)p0.z,(f16)p0.w,
                      (f16)p1.x,(f16)p1.y,(f16)p1.z,(f16)p1.w };
        half8v a1 = { (f16)p2.x,(f16)p2.y,(f16)p2.z,(f16)p2.w,
                      (f16)p3.x,(f16)p3.y,(f16)p3.z,(f16)p3.w };

        f32x4v acc[3];
        #pragma unroll
        for (int t = 0; t < 3; t++) {
            f32x4v a = {0.0f, 0.0f, 0.0f, 0.0f};
            a = __builtin_amdgcn_mfma_f32_16x16x32_f16(a0, bfr[t][0], a, 0, 0, 0);
            a = __builtin_amdgcn_mfma_f32_16x16x32_f16(a1, bfr[t][1], a, 0, 0, 0);
            acc[t] = a;
        }

        // epilogue: C row = row0 + quad*4 + r; col c -> (plane, jjloc)
        int jp  = (col & 7) >> 1;
        int sub = col & 1;
        #pragma unroll
        for (int r = 0; r < 4; r++) {
            int row = row0 + quad * 4 + r;
            if (row < N_NODES) {
                int hb = (row * 5 + jp) * 8 + sub * 4;
                #pragma unroll
                for (int t = 0; t < 3; t++) {
                    int plane = 2 * t + (col >> 3);
                    f16 v = (f16)acc[t][r];
                    if (plane < 3) sUh[hb + plane] = v;
                    else           sVh[hb + (plane - 3)] = v;
                }
                if (col < 8) {   // one writer per (row, jj): raw state value
                    float svv = state[sbase + (size_t)row * H_ + jjglob];
                    sUh[hb + 3] = (f16)svv;
                }
            }
        }
    }
    __syncthreads();

    // ---- Phase 2: segment softmax from LDS (edge records double-buffered)
    float sg = sigmoidf_(gate[0]);
    int jp   = tid & 3;      // jj pair within the eighth
    int slot = tid >> 2;     // 0..127

    const uint4* ep4 = (const uint4*)edge_pack;   // 2 edges per uint4
    const char*  sUb = (const char*)sU;
    int jpo = jp << 4;

    int n = slot;
    uint4 E[8];
    #pragma unroll
    for (int k = 0; k < 8; k++) E[k] = ep4[n * 8 + k];

    #pragma unroll 1
    for (int it = 0; it < 4; it++) {
        // prefetch next n's edge records while we chew on this one
        int nn = n + 128;
        int nsafe = (nn < N_NODES) ? nn : n;
        uint4 En[8];
        #pragma unroll
        for (int k = 0; k < 8; k++) En[k] = ep4[nsafe * 8 + k];

        float4 vraw = sV[n * 5 + jp];
        float2 vx = __half22float2(*(const __half2*)&vraw.x);  // vA0, vB0
        float2 vy = __half22float2(*(const __half2*)&vraw.y);  // vC0, -
        float2 vz = __half22float2(*(const __half2*)&vraw.z);  // vA1, vB1
        float2 vw = __half22float2(*(const __half2*)&vraw.w);  // vC1, -

        float l0 = 0.0f, num0 = 0.0f, l1 = 0.0f, num1 = 0.0f;
        #pragma unroll
        for (int e = 0; e < DEG; e++) {
            unsigned sxo = (e & 1) ? E[e >> 1].z : E[e >> 1].x;
            unsigned hx  = (e & 1) ? E[e >> 1].w : E[e >> 1].y;
            float2 hh = __half22float2(*(const __half2*)&hx);
            float4 u = *(const float4*)(sUb + sxo + jpo);
            float2 ux = __half22float2(*(const __half2*)&u.x);  // uA0, uB0
            float2 uy = __half22float2(*(const __half2*)&u.y);  // uC0, uS0
            float2 uz = __half22float2(*(const __half2*)&u.z);  // uA1, uB1
            float2 uw = __half22float2(*(const __half2*)&u.w);  // uC1, uS1
            float a0 = fmaf(hh.x, ux.x + vx.x, fmaf(hh.y, ux.y + vx.y, uy.x + vy.x));
            float a1 = fmaf(hh.x, uz.x + vz.x, fmaf(hh.y, uz.y + vz.y, uw.x + vw.x));
            a0 = fmaxf(a0, 0.01f * a0);            // leaky_relu 0.01 (log2e pre-scaled)
            a1 = fmaxf(a1, 0.01f * a1);
            float p0 = EXP2F(a0);
            float p1 = EXP2F(a1);
            l0 += p0;  num0 = fmaf(p0, uy.y, num0);
            l1 += p1;  num1 = fmaf(p1, uw.y, num1);
        }
        float2 r;
        r.x = fmaxf(num0 / l0, 0.0f) * sg;
        r.y = fmaxf(num1 / l1, 0.0f) * sg;
        out2[((size_t)bt * N_NODES + n) * 32 + jh * 4 + jp] = r;

        n = nn;
        if (n >= N_NODES) break;
        #pragma unroll
        for (int k = 0; k < 8; k++) E[k] = En[k];
    }
}

// ---------------------------------------------------------------------------
// Workspace layout (bytes):
//   [0, 64000)        edge_pack (E uint2)
//   [131072, +49152)  wTh       (6*64*64 fp16, log2e-scaled)   total < 0.2 MB
// ---------------------------------------------------------------------------
extern "C" void kernel_launch(void* const* d_in, const int* in_sizes, int n_in,
                              void* d_out, int out_size, void* d_ws, size_t ws_size,
                              hipStream_t stream) {
    const float* state   = (const float*)d_in[0];
    const float* feature = (const float*)d_in[1];
    const float* dist    = (const float*)d_in[2];
    const float* W1      = (const float*)d_in[3];
    const float* b1      = (const float*)d_in[4];
    const float* W2      = (const float*)d_in[5];
    const float* b2      = (const float*)d_in[6];
    const float* W3      = (const float*)d_in[7];
    const float* b3      = (const float*)d_in[8];
    const float* gate    = (const float*)d_in[9];
    const int*   src     = (const int*)d_in[10];
    const int*   dst     = (const int*)d_in[11];
    float* out = (float*)d_out;
    (void)dst;

    char* ws = (char*)d_ws;
    uint2* edge_pack = (uint2*)(ws);
    f16*   wTh       = (f16*)(ws + 131072ULL);

    hipLaunchKernelGGL(prep_kernel, dim3(128), dim3(256), 0, stream,
                       feature, dist, W1, b1, W2, b2, src, W3, b3,
                       edge_pack, wTh);
    hipLaunchKernelGGL(fused_kernel, dim3(BT * 8), dim3(512), 0, stream,
                       state, wTh, edge_pack, gate, (float2*)out);
}

// Round 11
// 127.254 us; speedup vs baseline: 1.2594x; 1.0231x over previous
//
#include <hip/hip_runtime.h>
#include <hip/hip_fp16.h>
#include <math.h>

// Problem constants: N=500, DEG=16, E=8000, B=8, T=12 (BT=96), H=64, F=32
#define N_NODES 500
#define DEG     16
#define E_EDGES 8000
#define BT      96
#define H_      64
#define F_      32

typedef _Float16 f16;
typedef f16   half8v  __attribute__((ext_vector_type(8)));
typedef f16   half4v  __attribute__((ext_vector_type(4)));
typedef f16   half2v  __attribute__((ext_vector_type(2)));
typedef float f32x4v  __attribute__((ext_vector_type(4)));

#if __has_builtin(__builtin_amdgcn_exp2f)
#define EXP2F(x) __builtin_amdgcn_exp2f(x)
#else
#define EXP2F(x) exp2f(x)
#endif

#define LOG2E 1.44269504088896f

__device__ __forceinline__ float sigmoidf_(float x) {
    return 1.0f / (1.0f + __expf(-x));
}

__device__ __forceinline__ float dot2f_(half2v a, half2v b, float c) {
#if __has_builtin(__builtin_amdgcn_fdot2)
    return __builtin_amdgcn_fdot2(a, b, c, false);
#else
    return fmaf((float)a.x, (float)b.x, fmaf((float)a.y, (float)b.y, c));
#endif
}

// ---------------------------------------------------------------------------
// Kernel P (fused prep): blocks 0..31 = hyper MLP -> edge_pack
// {src*80 (LDS byte offset), h0h1 fp16x2}; blocks 32..127 = weight transpose
// -> wTh[c][jj][h] fp16, PRE-SCALED by log2(e) (leaky commutes with positive
// scale; fused kernel uses exp2 directly).
// plane c: 0=A_U 1=B_U 2=C_U 3=A_V 4=B_V 5=C_V; A=W3[0].view(128,64),
// B=W3[1], C=b3; U rows 0..63, V rows 64..127.
// ---------------------------------------------------------------------------
__global__ __launch_bounds__(256) void prep_kernel(
        const float* __restrict__ feature, const float* __restrict__ dist,
        const float* __restrict__ W1, const float* __restrict__ b1,
        const float* __restrict__ W2, const float* __restrict__ b2,
        const int* __restrict__ src,
        const float* __restrict__ W3, const float* __restrict__ b3,
        uint2* __restrict__ edge_pack, f16* __restrict__ wTh) {
    if (blockIdx.x >= 32) {
        int i = (blockIdx.x - 32) * 256 + threadIdx.x;
        if (i >= 6 * 64 * 64) return;
        int c  = i >> 12;
        int jj = (i >> 6) & 63;
        int h  = i & 63;
        const float* plane = (c % 3 == 0) ? W3 : (c % 3 == 1) ? (W3 + 8192) : b3;
        int rowbase = (c < 3) ? 0 : 64;
        wTh[i] = (f16)(plane[(rowbase + h) * 64 + jj] * LOG2E);
        return;
    }

    __shared__ float sW1[65 * 16];
    __shared__ float sb1[16];
    __shared__ float sW2[32];
    __shared__ float sb2[2];
    for (int i = threadIdx.x; i < 65 * 16; i += blockDim.x) sW1[i] = W1[i];
    if (threadIdx.x < 16) sb1[threadIdx.x] = b1[threadIdx.x];
    if (threadIdx.x < 32) sW2[threadIdx.x] = W2[threadIdx.x];
    if (threadIdx.x < 2)  sb2[threadIdx.x] = b2[threadIdx.x];
    __syncthreads();

    int e = blockIdx.x * 256 + threadIdx.x;
    if (e >= E_EDGES) return;
    int s = src[e];
    int d = e >> 4;                 // dst = repeat(arange(500),16)
    float fs[F_], fd[F_];
    const float4* f4 = (const float4*)feature;
    #pragma unroll
    for (int k = 0; k < 8; k++) {
        float4 v = f4[s * 8 + k];
        fs[4*k] = v.x; fs[4*k+1] = v.y; fs[4*k+2] = v.z; fs[4*k+3] = v.w;
    }
    #pragma unroll
    for (int k = 0; k < 8; k++) {
        float4 v = f4[d * 8 + k];
        fd[4*k] = v.x; fd[4*k+1] = v.y; fd[4*k+2] = v.z; fd[4*k+3] = v.w;
    }
    float dv = dist[e];

    float h1v[16];
    #pragma unroll
    for (int m = 0; m < 16; m++) {
        float acc = sb1[m] + dv * sW1[64 * 16 + m];
        #pragma unroll
        for (int f = 0; f < F_; f++) acc += fs[f] * sW1[f * 16 + m];
        #pragma unroll
        for (int f = 0; f < F_; f++) acc += fd[f] * sW1[(F_ + f) * 16 + m];
        h1v[m] = sigmoidf_(acc);
    }
    float o0 = sb2[0], o1 = sb2[1];
    #pragma unroll
    for (int m = 0; m < 16; m++) {
        o0 += h1v[m] * sW2[m * 2 + 0];
        o1 += h1v[m] * sW2[m * 2 + 1];
    }
    __half2 hh = __floats2half2_rn(sigmoidf_(o0), sigmoidf_(o1));
    uint2 ep;
    ep.x = (unsigned)(s * 80);      // pre-multiplied sU row byte-offset
    ep.y = *(unsigned*)&hh;
    edge_pack[e] = ep;
}

// ---------------------------------------------------------------------------
// Kernel F (fused GEMM + segment softmax). Grid = 8 jh x 96 bt, jh-major
// (R10: dropped FETCH 48.5 -> 6.7 MB). 512 thr (8 waves), LDS 80 KB.
//
// Phase 1: slice GEMM via mfma_f32_16x16x32_f16. Tile t covers plane
//   t + 3*(col>>3): a col<8 lane's three accs are {uA,uB,uC} (all U),
//   col>=8 gives {vA,vB,vC} -> epilogue packs {A,B,C,S} / {A,B,C,0} as ONE
//   ds_write_b64 per row (R10: 13 scattered b16/thread-pass -> 2.36M
//   conflict cycles).
// Phase 2: packed-fp16 softmax: hh consumed as raw half2, pk_add for
//   {A,B} and {C,S} pairs, v_dot2_f32_f16 for the h-contraction; exp2 in
//   f32 (alpha*log2e can exceed fp16 exp range). ~18 ops/edge vs R10's ~28.
// ---------------------------------------------------------------------------
__global__ __launch_bounds__(512, 4) void fused_kernel(
        const float* __restrict__ state,
        const f16* __restrict__ wTh,
        const uint2* __restrict__ edge_pack,
        const float* __restrict__ gate,
        float2* __restrict__ out2) {
    __shared__ float4 sU[N_NODES * 5];   // 40 KB, 80 B per node row
    __shared__ float4 sV[N_NODES * 5];   // 40 KB

    int bt  = blockIdx.x % BT;
    int jh  = blockIdx.x / BT;
    int tid = threadIdx.x;
    int wv   = tid >> 6;
    int lane = tid & 63;
    int col  = lane & 15;
    int quad = lane >> 4;

    // B fragments: tile t covers plane t + 3*(col>>3), jj = jh*8 + (col&7)
    int jjglob = jh * 8 + (col & 7);
    int pside  = col >> 3;              // 0 = U planes, 1 = V planes
    half8v bfr[3][2];
    #pragma unroll
    for (int t = 0; t < 3; t++) {
        int plane = t + 3 * pside;
        const f16* wp = wTh + (plane * 64 + jjglob) * 64;
        bfr[t][0] = *(const half8v*)&wp[quad * 8];
        bfr[t][1] = *(const half8v*)&wp[32 + quad * 8];
    }

    const size_t sbase = (size_t)bt * N_NODES * H_;
    char* dstBase = (char*)(pside ? sV : sU);

    // ---- Phase 1: GEMM into LDS pack
    for (int pass = 0; pass < 4; pass++) {
        int row0 = pass * 128 + wv * 16;
        int arow = row0 + col;
        int arowc = arow < N_NODES ? arow : N_NODES - 1;   // clamp tail reads
        const float* srow = state + sbase + (size_t)arowc * H_;
        float4 p0 = *(const float4*)&srow[quad * 8];
        float4 p1 = *(const float4*)&srow[quad * 8 + 4];
        float4 p2 = *(const float4*)&srow[32 + quad * 8];
        float4 p3 = *(const float4*)&srow[32 + quad * 8 + 4];
        half8v a0 = { (f16)p0.x,(f16)p0.y,(f16)p0.z,(f16)p0.w,
                      (f16)p1.x,(f16)p1.y,(f16)p1.z,(f16)p1.w };
        half8v a1 = { (f16)p2.x,(f16)p2.y,(f16)p2.z,(f16)p2.w,
                      (f16)p3.x,(f16)p3.y,(f16)p3.z,(f16)p3.w };

        f32x4v acc[3];
        #pragma unroll
        for (int t = 0; t < 3; t++) {
            f32x4v a = {0.0f, 0.0f, 0.0f, 0.0f};
            a = __builtin_amdgcn_mfma_f32_16x16x32_f16(a0, bfr[t][0], a, 0, 0, 0);
            a = __builtin_amdgcn_mfma_f32_16x16x32_f16(a1, bfr[t][1], a, 0, 0, 0);
            acc[t] = a;
        }

        // epilogue: one ds_write_b64 per row r
        int jp  = (col & 7) >> 1;
        int sub = col & 1;
        #pragma unroll
        for (int r = 0; r < 4; r++) {
            int row = row0 + quad * 4 + r;
            if (row < N_NODES) {
                // 4th half: U side carries state value, V side carries 0
                f16 last = (f16)0.0f;
                if (!pside) last = (f16)state[sbase + (size_t)row * H_ + jjglob];
                half4v pack = { (f16)acc[0][r], (f16)acc[1][r], (f16)acc[2][r], last };
                int boff = (row * 5 + jp) * 16 + sub * 8;
                *(half4v*)(dstBase + boff) = pack;
            }
        }
    }
    __syncthreads();

    // ---- Phase 2: packed-fp16 segment softmax from LDS
    float sg = sigmoidf_(gate[0]);
    int jp   = tid & 3;      // jj pair within the eighth
    int slot = tid >> 2;     // 0..127

    const uint4* ep4 = (const uint4*)edge_pack;   // 2 edges per uint4
    const char*  sUb = (const char*)sU;
    int jpo = jp << 4;

    int n = slot;
    uint4 E[8];
    #pragma unroll
    for (int k = 0; k < 8; k++) E[k] = ep4[n * 8 + k];

    #pragma unroll 1
    for (int it = 0; it < 4; it++) {
        // prefetch next n's edge records while we chew on this one
        int nn = n + 128;
        int nsafe = (nn < N_NODES) ? nn : n;
        uint4 En[8];
        #pragma unroll
        for (int k = 0; k < 8; k++) En[k] = ep4[nsafe * 8 + k];

        float4 vraw = sV[n * 5 + jp];
        half2v vAB0 = *(half2v*)&vraw.x;   // {vA0, vB0}
        half2v vCS0 = *(half2v*)&vraw.y;   // {vC0, 0}
        half2v vAB1 = *(half2v*)&vraw.z;   // {vA1, vB1}
        half2v vCS1 = *(half2v*)&vraw.w;   // {vC1, 0}

        float l0 = 0.0f, num0 = 0.0f, l1 = 0.0f, num1 = 0.0f;
        #pragma unroll
        for (int e = 0; e < DEG; e++) {
            unsigned sxo = (e & 1) ? E[e >> 1].z : E[e >> 1].x;
            unsigned hx  = (e & 1) ? E[e >> 1].w : E[e >> 1].y;
            half2v hh = *(half2v*)&hx;
            float4 u = *(const float4*)(sUb + sxo + jpo);
            half2v uAB0 = *(half2v*)&u.x;   // {uA0, uB0}
            half2v uCS0 = *(half2v*)&u.y;   // {uC0, uS0}
            half2v uAB1 = *(half2v*)&u.z;
            half2v uCS1 = *(half2v*)&u.w;

            half2v ab0 = uAB0 + vAB0;       // v_pk_add_f16
            half2v ab1 = uAB1 + vAB1;
            half2v cs0 = uCS0 + vCS0;       // {C-term, S} (vS slot is 0)
            half2v cs1 = uCS1 + vCS1;

            float a0 = dot2f_(hh, ab0, (float)cs0.x);
            float a1 = dot2f_(hh, ab1, (float)cs1.x);
            a0 = fmaxf(a0, 0.01f * a0);     // leaky_relu (log2e pre-scaled)
            a1 = fmaxf(a1, 0.01f * a1);
            float p0 = EXP2F(a0);
            float p1 = EXP2F(a1);
            l0 += p0;  num0 = fmaf(p0, (float)cs0.y, num0);
            l1 += p1;  num1 = fmaf(p1, (float)cs1.y, num1);
        }
        float2 r;
        r.x = fmaxf(num0 / l0, 0.0f) * sg;
        r.y = fmaxf(num1 / l1, 0.0f) * sg;
        out2[((size_t)bt * N_NODES + n) * 32 + jh * 4 + jp] = r;

        n = nn;
        if (n >= N_NODES) break;
        #pragma unroll
        for (int k = 0; k < 8; k++) E[k] = En[k];
    }
}

// ---------------------------------------------------------------------------
// Workspace layout (bytes):
//   [0, 64000)        edge_pack (E uint2)
//   [131072, +49152)  wTh       (6*64*64 fp16, log2e-scaled)   total < 0.2 MB
// ---------------------------------------------------------------------------
extern "C" void kernel_launch(void* const* d_in, const int* in_sizes, int n_in,
                              void* d_out, int out_size, void* d_ws, size_t ws_size,
                              hipStream_t stream) {
    const float* state   = (const float*)d_in[0];
    const float* feature = (const float*)d_in[1];
    const float* dist    = (const float*)d_in[2];
    const float* W1      = (const float*)d_in[3];
    const float* b1      = (const float*)d_in[4];
    const float* W2      = (const float*)d_in[5];
    const float* b2      = (const float*)d_in[6];
    const float* W3      = (const float*)d_in[7];
    const float* b3      = (const float*)d_in[8];
    const float* gate    = (const float*)d_in[9];
    const int*   src     = (const int*)d_in[10];
    const int*   dst     = (const int*)d_in[11];
    float* out = (float*)d_out;
    (void)dst;

    char* ws = (char*)d_ws;
    uint2* edge_pack = (uint2*)(ws);
    f16*   wTh       = (f16*)(ws + 131072ULL);

    hipLaunchKernelGGL(prep_kernel, dim3(128), dim3(256), 0, stream,
                       feature, dist, W1, b1, W2, b2, src, W3, b3,
                       edge_pack, wTh);
    hipLaunchKernelGGL(fused_kernel, dim3(BT * 8), dim3(512), 0, stream,
                       state, wTh, edge_pack, gate, (float2*)out);
}